// Round 5
// baseline (187.656 us; speedup 1.0000x reference)
//
#include <hip/hip_runtime.h>
#include <hip/hip_bf16.h>

// AngleProtoLoss: loss = -mean_n logsoftmax(clip(cos(last_n,cent_k),1e-6)*w+b)[n,n]
// Identity: loss_n = ln2*(log2(sum_k 2^{z_nk}) - z_nn), z = clamp(cos*w*log2e); b cancels.
// k1: centroids+norms -> unit cent (bf16), w*log2e-prescaled unit last (bf16), fp32 z_nn.
// k2: NO LDS, NO barriers: cent (2 MB) fits in every XCD L2, so each wave streams its
//     B fragments straight from global with a 1-step register ping-pong prefetch.
//     Wave owns 64 rows (A frags in regs) x 256 cols; per-chunk partial sums written
//     non-atomically to spart[32][8192].
// k3: single block: S_n = sum_c spart[c][n]; loss = ln2/N * sum_n (log2(S_n) - z_nn).

typedef __attribute__((ext_vector_type(8))) short short8;
typedef __attribute__((ext_vector_type(4))) float f32x4;

#define NSPK 8192
#define DEMB 128
#define MUTT 10
#define LOG2E 1.44269504088896340736f
#define LN2   0.69314718055994530942f
#define NCHUNK 32

// workspace: floats [0,8192) = zdiag, [8192, 8192+32*8192) = spart; then bf16 matrices
#define WS_ZDIAG 0
#define WS_SPART 8192
#define WS_LASTB 1114112    // byte offset, 2 MB
#define WS_CENTB 3211264    // byte offset, 2 MB

__global__ __launch_bounds__(256) void k1_prep(const float* __restrict__ x,
                                               const float* __restrict__ wp,
                                               float* __restrict__ W,
                                               __hip_bfloat16* __restrict__ lastb,
                                               __hip_bfloat16* __restrict__ centb) {
    const int wv = threadIdx.x >> 6;
    const int l  = threadIdx.x & 63;
    const int n  = blockIdx.x * 4 + wv;           // one wave per speaker

    const float* xr = x + (size_t)n * (MUTT * DEMB) + 2 * l;   // lane owns dims 2l,2l+1
    float sx = 0.f, sy = 0.f, vx = 0.f, vy = 0.f;
#pragma unroll
    for (int m = 0; m < MUTT; ++m) {
        float2 t = *(const float2*)(xr + m * DEMB);
        vx = t.x; vy = t.y; sx += t.x; sy += t.y;
    }
    const float cx = sx * 0.1f, cy = sy * 0.1f;   // centroid dims
    float sl = vx * vx + vy * vy;                 // |last|^2 partial
    float sc = cx * cx + cy * cy;                 // |cent|^2 partial
    float dp = vx * cx + vy * cy;                 // last.cent partial (diag)
#pragma unroll
    for (int off = 1; off < 64; off <<= 1) {
        sl += __shfl_xor(sl, off);
        sc += __shfl_xor(sc, off);
        dp += __shfl_xor(dp, off);
    }
    const float il = rsqrtf(sl), ic = rsqrtf(sc);
    const float scale = wp[0] * LOG2E;
    const float as = il * scale;                  // prescale last by w*log2e
    __hip_bfloat162 lv, cv;
    lv.x = __float2bfloat16(vx * as); lv.y = __float2bfloat16(vy * as);
    cv.x = __float2bfloat16(cx * ic); cv.y = __float2bfloat16(cy * ic);
    *(__hip_bfloat162*)(lastb + n * DEMB + 2 * l) = lv;
    *(__hip_bfloat162*)(centb + n * DEMB + 2 * l) = cv;
    if (l == 0) {
        const float lo = scale >= 0.f ? 1e-6f * scale : -INFINITY;
        const float hi = scale >= 0.f ? INFINITY : 1e-6f * scale;
        W[WS_ZDIAG + n] = fminf(fmaxf(dp * il * ic * scale, lo), hi);
    }
}

// grid (32,32): 256-row block x 256-col chunk. 4 waves/block; wave owns 64 rows x 256 cols.
// No LDS, no __syncthreads: B streamed from L2 with register ping-pong prefetch.
__global__ __launch_bounds__(256, 3) void k2_main(
        const __hip_bfloat16* __restrict__ lastb,
        const __hip_bfloat16* __restrict__ centb,
        const float* __restrict__ wp,
        float* __restrict__ W) {
    const int tid  = threadIdx.x;
    const int lane = tid & 63;
    const int wv   = tid >> 6;
    const int quad = lane >> 4;
    const int l16  = lane & 15;
    const int R0   = blockIdx.x * 256;
    const int C0   = blockIdx.y * 256;
    const float scale = wp[0] * LOG2E;
    const float lo = scale >= 0.f ? 1e-6f * scale : -INFINITY;
    const float hi = scale >= 0.f ? INFINITY : 1e-6f * scale;

    // A fragments (held whole kernel): rows R0 + wv*64 + rt*16 + l16, k = quad*8 + kc*32
    short8 a[4][4];
    {
        const short* ap = (const short*)lastb + (size_t)(R0 + wv * 64 + l16) * DEMB + quad * 8;
#pragma unroll
        for (int rt = 0; rt < 4; ++rt)
#pragma unroll
            for (int kc = 0; kc < 4; ++kc)
                a[rt][kc] = *(const short8*)(ap + rt * 16 * DEMB + kc * 32);
    }

    // B fragment addr for (s-step, kc): cb + bbase + s*4096 + kc*64
    //   (B[n = C0+s*16+l16][k = quad*8 + kc*32 .. +8], row stride 256 B)
    const char* cb = (const char*)centb;
    const size_t bbase = ((size_t)(C0 + l16) << 8) + (quad << 4);

    short8 b0[4], b1[4];
#pragma unroll
    for (int kc = 0; kc < 4; ++kc)
        b0[kc] = *(const short8*)(cb + bbase + kc * 64);

    float racc[4][4] = {{0.f}};

#pragma unroll
    for (int s = 0; s < 16; ++s) {            // 16 ntiles of 16 cols
        const short8* bc = (s & 1) ? b1 : b0;
        short8*       bn = (s & 1) ? b0 : b1;
        if (s < 15) {
#pragma unroll
            for (int kc = 0; kc < 4; ++kc)
                bn[kc] = *(const short8*)(cb + bbase + (size_t)(s + 1) * 4096 + kc * 64);
        }
#pragma unroll
        for (int rt = 0; rt < 4; ++rt) {
            f32x4 acc = {0.f, 0.f, 0.f, 0.f};
#pragma unroll
            for (int kc = 0; kc < 4; ++kc)
                acc = __builtin_amdgcn_mfma_f32_16x16x32_bf16(a[rt][kc], bc[kc], acc, 0, 0, 0);
            // C layout: col = l16, row = quad*4 + r; acc is already z (A prescaled)
#pragma unroll
            for (int r = 0; r < 4; ++r) {
                const float z = fminf(fmaxf(acc[r], lo), hi);   // v_med3_f32
                racc[rt][r] += __builtin_amdgcn_exp2f(z);
            }
        }
    }
    // reduce row sums over the 16 l16-lanes holding the same rows
#pragma unroll
    for (int off = 1; off < 16; off <<= 1)
#pragma unroll
        for (int rt = 0; rt < 4; ++rt)
#pragma unroll
            for (int r = 0; r < 4; ++r)
                racc[rt][r] += __shfl_xor(racc[rt][r], off);
    if (l16 == 0) {
#pragma unroll
        for (int rt = 0; rt < 4; ++rt)
#pragma unroll
            for (int r = 0; r < 4; ++r)
                W[WS_SPART + blockIdx.y * NSPK + R0 + wv * 64 + rt * 16 + quad * 4 + r]
                    = racc[rt][r];
    }
}

__global__ __launch_bounds__(256) void k3_loss(const float* __restrict__ W,
                                               float* __restrict__ out) {
    float v = 0.f;
    for (int n = threadIdx.x; n < NSPK; n += 256) {
        float S = 0.f;
#pragma unroll
        for (int c = 0; c < NCHUNK; ++c) S += W[WS_SPART + c * NSPK + n];
        v += __log2f(S) - W[WS_ZDIAG + n];
    }
#pragma unroll
    for (int off = 1; off < 64; off <<= 1) v += __shfl_xor(v, off);
    __shared__ float red[4];
    if ((threadIdx.x & 63) == 0) red[threadIdx.x >> 6] = v;
    __syncthreads();
    if (threadIdx.x == 0)
        out[0] = (red[0] + red[1] + red[2] + red[3]) * (LN2 / (float)NSPK);
}

extern "C" void kernel_launch(void* const* d_in, const int* in_sizes, int n_in,
                              void* d_out, int out_size, void* d_ws, size_t ws_size,
                              hipStream_t stream) {
    const float* x = (const float*)d_in[0];
    const float* w = (const float*)d_in[1];
    // b (d_in[2]) cancels analytically — unused.
    float* W = (float*)d_ws;
    __hip_bfloat16* lastb = (__hip_bfloat16*)((char*)d_ws + WS_LASTB);
    __hip_bfloat16* centb = (__hip_bfloat16*)((char*)d_ws + WS_CENTB);

    k1_prep<<<NSPK / 4, 256, 0, stream>>>(x, w, W, lastb, centb);
    k2_main<<<dim3(32, 32), 256, 0, stream>>>(lastb, centb, w, W);
    k3_loss<<<1, 256, 0, stream>>>(W, (float*)d_out);
}

// Round 6
// 130.609 us; speedup vs baseline: 1.4368x; 1.4368x over previous
//
#include <hip/hip_runtime.h>
#include <hip/hip_bf16.h>

// AngleProtoLoss: loss = -mean_n logsoftmax(clip(cos(last_n,cent_k),1e-6)*w+b)[n,n]
// Identity: loss_n = ln2*(log2(sum_k 2^{z_nk}) - z_nn), z = clamp(cos*w*log2e); b cancels.
// k1: centroids+norms -> unit cent (bf16), w*log2e-prescaled unit last (bf16), fp32 z_nn;
//     zeroes zsum.
// k2: NO LDS, NO barriers: cent (2 MB) fits in every XCD L2; each wave streams its B
//     fragments straight from global (L2 hits) with 1-step register ping-pong prefetch.
//     Wave owns 64 rows (A frags in regs) x 256 cols. launch_bounds(256,2): 256-reg
//     budget -> 128 VGPR + 128 AGPR halves, NO spill (the (256,3)/(256,4) bounds made
//     the allocator halve the file and spill -> 126 MB scratch writes in rounds 4/5).
// k3: single block: loss = ln2/N * sum_n (log2(zsum_n) - z_nn).

typedef __attribute__((ext_vector_type(8))) short short8;
typedef __attribute__((ext_vector_type(4))) float f32x4;

#define NSPK 8192
#define DEMB 128
#define MUTT 10
#define LOG2E 1.44269504088896340736f
#define LN2   0.69314718055994530942f

// workspace: floats [0,8192) = zdiag, [8192,16384) = zsum; then bf16 matrices
#define WS_ZDIAG 0
#define WS_ZSUM  8192
#define WS_LASTB 65536      // byte offset, 2 MB
#define WS_CENTB 2162688    // byte offset, 2 MB

__global__ __launch_bounds__(256) void k1_prep(const float* __restrict__ x,
                                               const float* __restrict__ wp,
                                               float* __restrict__ W,
                                               __hip_bfloat16* __restrict__ lastb,
                                               __hip_bfloat16* __restrict__ centb) {
    const int wv = threadIdx.x >> 6;
    const int l  = threadIdx.x & 63;
    const int n  = blockIdx.x * 4 + wv;           // one wave per speaker
    if (blockIdx.x < 32) W[WS_ZSUM + blockIdx.x * 256 + threadIdx.x] = 0.f;

    const float* xr = x + (size_t)n * (MUTT * DEMB) + 2 * l;   // lane owns dims 2l,2l+1
    float sx = 0.f, sy = 0.f, vx = 0.f, vy = 0.f;
#pragma unroll
    for (int m = 0; m < MUTT; ++m) {
        float2 t = *(const float2*)(xr + m * DEMB);
        vx = t.x; vy = t.y; sx += t.x; sy += t.y;
    }
    const float cx = sx * 0.1f, cy = sy * 0.1f;   // centroid dims
    float sl = vx * vx + vy * vy;                 // |last|^2 partial
    float sc = cx * cx + cy * cy;                 // |cent|^2 partial
    float dp = vx * cx + vy * cy;                 // last.cent partial (diag)
#pragma unroll
    for (int off = 1; off < 64; off <<= 1) {
        sl += __shfl_xor(sl, off);
        sc += __shfl_xor(sc, off);
        dp += __shfl_xor(dp, off);
    }
    const float il = rsqrtf(sl), ic = rsqrtf(sc);
    const float scale = wp[0] * LOG2E;
    const float as = il * scale;                  // prescale last by w*log2e
    __hip_bfloat162 lv, cv;
    lv.x = __float2bfloat16(vx * as); lv.y = __float2bfloat16(vy * as);
    cv.x = __float2bfloat16(cx * ic); cv.y = __float2bfloat16(cy * ic);
    *(__hip_bfloat162*)(lastb + n * DEMB + 2 * l) = lv;
    *(__hip_bfloat162*)(centb + n * DEMB + 2 * l) = cv;
    if (l == 0) {
        const float lo = scale >= 0.f ? 1e-6f * scale : -INFINITY;
        const float hi = scale >= 0.f ? INFINITY : 1e-6f * scale;
        W[WS_ZDIAG + n] = fminf(fmaxf(dp * il * ic * scale, lo), hi);
    }
}

// grid (32,32): 256-row block x 256-col chunk. 4 waves/block; wave owns 64 rows x 256 cols.
// No LDS, no __syncthreads: B streamed from L2 with register ping-pong prefetch.
__global__ __launch_bounds__(256, 2) void k2_main(
        const __hip_bfloat16* __restrict__ lastb,
        const __hip_bfloat16* __restrict__ centb,
        const float* __restrict__ wp,
        float* __restrict__ W) {
    const int tid  = threadIdx.x;
    const int lane = tid & 63;
    const int wv   = tid >> 6;
    const int quad = lane >> 4;
    const int l16  = lane & 15;
    const int R0   = blockIdx.x * 256;
    const int C0   = blockIdx.y * 256;
    const float scale = wp[0] * LOG2E;
    const float lo = scale >= 0.f ? 1e-6f * scale : -INFINITY;
    const float hi = scale >= 0.f ? INFINITY : 1e-6f * scale;

    // A fragments (held whole kernel): rows R0 + wv*64 + rt*16 + l16, k = quad*8 + kc*32
    short8 a[4][4];
    {
        const short* ap = (const short*)lastb + (size_t)(R0 + wv * 64 + l16) * DEMB + quad * 8;
#pragma unroll
        for (int rt = 0; rt < 4; ++rt)
#pragma unroll
            for (int kc = 0; kc < 4; ++kc)
                a[rt][kc] = *(const short8*)(ap + rt * 16 * DEMB + kc * 32);
    }

    // B fragment addr for (s-step, kc): cb + bbase + s*4096 + kc*64
    //   (B[n = C0+s*16+l16][k = quad*8 + kc*32 .. +8], row stride 256 B)
    const char* cb = (const char*)centb;
    const size_t bbase = ((size_t)(C0 + l16) << 8) + (quad << 4);

    short8 b0[4], b1[4];
#pragma unroll
    for (int kc = 0; kc < 4; ++kc)
        b0[kc] = *(const short8*)(cb + bbase + kc * 64);

    float racc[4][4] = {{0.f}};

#pragma unroll
    for (int s = 0; s < 16; ++s) {            // 16 ntiles of 16 cols
        const short8* bc = (s & 1) ? b1 : b0;
        short8*       bn = (s & 1) ? b0 : b1;
        if (s < 15) {
#pragma unroll
            for (int kc = 0; kc < 4; ++kc)
                bn[kc] = *(const short8*)(cb + bbase + (size_t)(s + 1) * 4096 + kc * 64);
        }
#pragma unroll
        for (int rt = 0; rt < 4; ++rt) {
            f32x4 acc = {0.f, 0.f, 0.f, 0.f};
#pragma unroll
            for (int kc = 0; kc < 4; ++kc)
                acc = __builtin_amdgcn_mfma_f32_16x16x32_bf16(a[rt][kc], bc[kc], acc, 0, 0, 0);
            // C layout: col = l16, row = quad*4 + r; acc is already z (A prescaled)
#pragma unroll
            for (int r = 0; r < 4; ++r) {
                const float z = fminf(fmaxf(acc[r], lo), hi);   // v_med3_f32
                racc[rt][r] += __builtin_amdgcn_exp2f(z);
            }
        }
    }
    // reduce row sums over the 16 l16-lanes holding the same rows
#pragma unroll
    for (int off = 1; off < 16; off <<= 1)
#pragma unroll
        for (int rt = 0; rt < 4; ++rt)
#pragma unroll
            for (int r = 0; r < 4; ++r)
                racc[rt][r] += __shfl_xor(racc[rt][r], off);
    if (l16 == 0) {
#pragma unroll
        for (int rt = 0; rt < 4; ++rt)
#pragma unroll
            for (int r = 0; r < 4; ++r)
                atomicAdd(&W[WS_ZSUM + R0 + wv * 64 + rt * 16 + quad * 4 + r], racc[rt][r]);
    }
}

__global__ __launch_bounds__(256) void k3_loss(const float* __restrict__ W,
                                               float* __restrict__ out) {
    float v = 0.f;
    for (int n = threadIdx.x; n < NSPK; n += 256)
        v += __log2f(W[WS_ZSUM + n]) - W[WS_ZDIAG + n];
#pragma unroll
    for (int off = 1; off < 64; off <<= 1) v += __shfl_xor(v, off);
    __shared__ float red[4];
    if ((threadIdx.x & 63) == 0) red[threadIdx.x >> 6] = v;
    __syncthreads();
    if (threadIdx.x == 0)
        out[0] = (red[0] + red[1] + red[2] + red[3]) * (LN2 / (float)NSPK);
}

extern "C" void kernel_launch(void* const* d_in, const int* in_sizes, int n_in,
                              void* d_out, int out_size, void* d_ws, size_t ws_size,
                              hipStream_t stream) {
    const float* x = (const float*)d_in[0];
    const float* w = (const float*)d_in[1];
    // b (d_in[2]) cancels analytically — unused.
    float* W = (float*)d_ws;
    __hip_bfloat16* lastb = (__hip_bfloat16*)((char*)d_ws + WS_LASTB);
    __hip_bfloat16* centb = (__hip_bfloat16*)((char*)d_ws + WS_CENTB);

    k1_prep<<<NSPK / 4, 256, 0, stream>>>(x, w, W, lastb, centb);
    k2_main<<<dim3(32, 32), 256, 0, stream>>>(lastb, centb, w, W);
    k3_loss<<<1, 256, 0, stream>>>(W, (float*)d_out);
}